// Round 1
// baseline (275.927 us; speedup 1.0000x reference)
//
#include <hip/hip_runtime.h>

// PositionLinear + ReLU: out[t,:] = relu(W @ x[t,:] + b)
// x: [T=1048576][64] fp32, W: [64][64] fp32, b: [64] fp32, out: [T][64] fp32
// Memory-bound (512 MiB min traffic @ ~6.3 TB/s => ~85 us floor).
// One thread per token: x row in 64 VGPRs, W/b via wave-uniform scalar loads.

#define N_DIM 64
#define TOKENS (32u * 32768u)  // B * P = 1,048,576

__global__ __launch_bounds__(256) void poslin_relu_kernel(
    const float* __restrict__ x,
    const float* __restrict__ W,
    const float* __restrict__ bias,
    float* __restrict__ out)
{
    const size_t t = (size_t)blockIdx.x * blockDim.x + threadIdx.x;
    if (t >= TOKENS) return;

    // Load this token's 64 inputs into registers (16 x float4 = 256 B).
    const float4* __restrict__ xr = reinterpret_cast<const float4*>(x + t * N_DIM);
    float xv[N_DIM];
#pragma unroll
    for (int j = 0; j < 16; ++j) {
        float4 v = xr[j];
        xv[4 * j + 0] = v.x;
        xv[4 * j + 1] = v.y;
        xv[4 * j + 2] = v.z;
        xv[4 * j + 3] = v.w;
    }

    float4* __restrict__ orow = reinterpret_cast<float4*>(out + t * N_DIM);

    // 16 iterations x 256 FMA; W/bias indices are wave-uniform -> s_load path.
#pragma unroll 1
    for (int o = 0; o < N_DIM; o += 4) {
        float a0 = bias[o + 0];
        float a1 = bias[o + 1];
        float a2 = bias[o + 2];
        float a3 = bias[o + 3];
        const float* __restrict__ w0 = W + (size_t)(o + 0) * N_DIM;
        const float* __restrict__ w1 = W + (size_t)(o + 1) * N_DIM;
        const float* __restrict__ w2 = W + (size_t)(o + 2) * N_DIM;
        const float* __restrict__ w3 = W + (size_t)(o + 3) * N_DIM;
#pragma unroll
        for (int k = 0; k < N_DIM; ++k) {
            const float xk = xv[k];
            a0 = fmaf(xk, w0[k], a0);
            a1 = fmaf(xk, w1[k], a1);
            a2 = fmaf(xk, w2[k], a2);
            a3 = fmaf(xk, w3[k], a3);
        }
        float4 r;
        r.x = fmaxf(a0, 0.0f);
        r.y = fmaxf(a1, 0.0f);
        r.z = fmaxf(a2, 0.0f);
        r.w = fmaxf(a3, 0.0f);
        orow[o >> 2] = r;
    }
}

extern "C" void kernel_launch(void* const* d_in, const int* in_sizes, int n_in,
                              void* d_out, int out_size, void* d_ws, size_t ws_size,
                              hipStream_t stream) {
    const float* x    = (const float*)d_in[0];
    const float* W    = (const float*)d_in[1];
    const float* bias = (const float*)d_in[2];
    float* out        = (float*)d_out;

    const int block = 256;
    const int grid  = (int)((TOKENS + block - 1) / block);  // 4096 blocks
    poslin_relu_kernel<<<grid, block, 0, stream>>>(x, W, bias, out);
}